// Round 3
// baseline (488.488 us; speedup 1.0000x reference)
//
#include <hip/hip_runtime.h>
#include <stdint.h>

#define BATCH 128
#define SEQL  512
#define FDIM  768
#define CTAGS 52
#define START_IDX 50
#define STOP_IDX  51
#define NEG_INF (-3.0e38f)

// ---------------------------------------------------------------------------
// K1: emission GEMM, register-only. Each wave: lane = output tag (52 of 64),
// RPW=8 consecutive rows. W row per-lane in VGPRs; F values are wave-uniform
// (scalar-load / broadcast). No LDS, no barriers, ~24 VGPR -> max occupancy.
// ---------------------------------------------------------------------------
#define RPW 8

__global__ __launch_bounds__(256) void emit_gemm2(
    const float* __restrict__ F, const float* __restrict__ W,
    const float* __restrict__ bias, float* __restrict__ emit)
{
    const int lane = threadIdx.x & 63;
    const int wv   = __builtin_amdgcn_readfirstlane(threadIdx.x >> 6);
    const int cc   = (lane < CTAGS) ? lane : (CTAGS - 1);
    const int row0 = (blockIdx.x * 4 + wv) * RPW;

    const float* wp = W + (size_t)cc * FDIM;
    const float* fp = F + (size_t)row0 * FDIM;

    float acc[RPW];
#pragma unroll
    for (int r = 0; r < RPW; ++r) acc[r] = 0.f;

    for (int k0 = 0; k0 < FDIM; k0 += 8) {
        float4 w0 = *(const float4*)(wp + k0);
        float4 w1 = *(const float4*)(wp + k0 + 4);
#pragma unroll
        for (int r = 0; r < RPW; ++r) {
            const float* fr = fp + (size_t)r * FDIM + k0;
            float f0 = fr[0], f1 = fr[1], f2 = fr[2], f3 = fr[3];
            float f4 = fr[4], f5 = fr[5], f6 = fr[6], f7 = fr[7];
            acc[r] = fmaf(f0, w0.x, acc[r]);
            acc[r] = fmaf(f1, w0.y, acc[r]);
            acc[r] = fmaf(f2, w0.z, acc[r]);
            acc[r] = fmaf(f3, w0.w, acc[r]);
            acc[r] = fmaf(f4, w1.x, acc[r]);
            acc[r] = fmaf(f5, w1.y, acc[r]);
            acc[r] = fmaf(f6, w1.z, acc[r]);
            acc[r] = fmaf(f7, w1.w, acc[r]);
        }
    }

    if (lane < CTAGS) {
        float bv = bias[lane];
#pragma unroll
        for (int r = 0; r < RPW; ++r)
            emit[(size_t)(row0 + r) * CTAGS + lane] = acc[r] + bv;
    }
}

// ---------------------------------------------------------------------------
// K2: serial Viterbi scan, MAX VALUE ONLY (no argmax index on the critical
// path). One wave per batch, lane = 'to'. Stores pre-update state each step
// into s_hist, which ALIASES emit (slot t's emission is consumed before slot
// t is overwritten; prefetch reads slot t+1 first).
// ---------------------------------------------------------------------------
__global__ __launch_bounds__(64) void viterbi_scan(
    const float* __restrict__ emit, const int* __restrict__ masks,
    const float* __restrict__ T, float* __restrict__ s_hist,
    float* __restrict__ out, int* __restrict__ btag)
{
    const int b  = blockIdx.x;
    const int to = threadIdx.x;
    const int toc = (to < CTAGS) ? to : (CTAGS - 1);

    float Trow[CTAGS];
#pragma unroll
    for (int f = 0; f < CTAGS; ++f) Trow[f] = T[toc * CTAGS + f];
    const float tstop = T[STOP_IDX * CTAGS + toc];

    const float* eb = emit   + (size_t)b * SEQL * CTAGS;
    const int*   mb = masks  + (size_t)b * SEQL;
    float*       sb = s_hist + (size_t)b * SEQL * CTAGS;

    float cur   = (to == START_IDX) ? 0.f : -10000.f;
    float e_cur = eb[toc];
    int   m_cur = mb[0];

    for (int t = 0; t < SEQL; ++t) {
        // prefetch next emission + mask (slot t+1) BEFORE overwriting slot t
        float e_nxt = 0.f;
        int   m_nxt = 0;
        if (t + 1 < SEQL) {
            e_nxt = eb[(size_t)(t + 1) * CTAGS + toc];
            m_nxt = mb[t + 1];
        }

        // store pre-update state (slot t's emission already in registers)
        if (to < CTAGS) sb[(size_t)t * CTAGS + to] = cur;

        // broadcast state to all lanes (uniform -> SGPR)
        const unsigned cu = __float_as_uint(cur);
        float a[CTAGS];
#pragma unroll
        for (int f = 0; f < CTAGS; ++f)
            a[f] = __uint_as_float(__builtin_amdgcn_readlane((int)cu, f)) + Trow[f];

        // max tree: 52 -> 17(+a51) -> 6 -> 2 -> 1
        float l1[17];
#pragma unroll
        for (int i = 0; i < 17; ++i)
            l1[i] = fmaxf(fmaxf(a[3 * i], a[3 * i + 1]), a[3 * i + 2]);
        float l2[6];
#pragma unroll
        for (int i = 0; i < 5; ++i)
            l2[i] = fmaxf(fmaxf(l1[3 * i], l1[3 * i + 1]), l1[3 * i + 2]);
        l2[5] = fmaxf(fmaxf(l1[15], l1[16]), a[51]);
        const float m = fmaxf(fmaxf(fmaxf(l2[0], l2[1]), l2[2]),
                              fmaxf(fmaxf(l2[3], l2[4]), l2[5]));

        cur   = m_cur ? (m + e_cur) : cur;
        e_cur = e_nxt;
        m_cur = m_nxt;
    }

    // final scores + wave argmax (first-index tiebreak)
    float v   = (to < CTAGS) ? (cur + tstop) : NEG_INF;
    int  bidx = to;
#pragma unroll
    for (int s = 1; s < 64; s <<= 1) {
        float ov = __shfl_xor(v, s);
        int   oi = __shfl_xor(bidx, s);
        if (ov > v || (ov == v && oi < bidx)) { v = ov; bidx = oi; }
    }
    if (to == 0) { out[b] = v; btag[b] = bidx; }
}

// ---------------------------------------------------------------------------
// K3: backpointers, fully parallel over (b,t). Wave processes 16 pairs with
// its T-row cached in registers. Max value is exact (same 52 inputs ->
// identical max whatever the tree), first-index tiebreak matches jnp.argmax.
// ---------------------------------------------------------------------------
#define PPW 16

__global__ __launch_bounds__(256) void bp_compute(
    const float* __restrict__ s_hist, const float* __restrict__ T,
    unsigned char* __restrict__ bp)
{
    const int lane = threadIdx.x & 63;
    const int wv   = __builtin_amdgcn_readfirstlane(threadIdx.x >> 6);
    const int toc  = (lane < CTAGS) ? lane : (CTAGS - 1);
    const int w    = blockIdx.x * 4 + wv;

    float Trow[CTAGS];
#pragma unroll
    for (int f = 0; f < CTAGS; ++f) Trow[f] = T[toc * CTAGS + f];

    for (int i = 0; i < PPW; ++i) {
        const int p = w * PPW + i;            // p = b*SEQL + t
        const float* sp = s_hist + (size_t)p * CTAGS;

        float a[CTAGS];
#pragma unroll
        for (int q = 0; q < 13; ++q) {
            float4 sv = *(const float4*)(sp + q * 4);  // wave-uniform
            a[q * 4 + 0] = sv.x + Trow[q * 4 + 0];
            a[q * 4 + 1] = sv.y + Trow[q * 4 + 1];
            a[q * 4 + 2] = sv.z + Trow[q * 4 + 2];
            a[q * 4 + 3] = sv.w + Trow[q * 4 + 3];
        }

        // max value tree
        float l1[17];
#pragma unroll
        for (int j = 0; j < 17; ++j)
            l1[j] = fmaxf(fmaxf(a[3 * j], a[3 * j + 1]), a[3 * j + 2]);
        float l2[6];
#pragma unroll
        for (int j = 0; j < 5; ++j)
            l2[j] = fmaxf(fmaxf(l1[3 * j], l1[3 * j + 1]), l1[3 * j + 2]);
        l2[5] = fmaxf(fmaxf(l1[15], l1[16]), a[51]);
        const float m = fmaxf(fmaxf(fmaxf(l2[0], l2[1]), l2[2]),
                              fmaxf(fmaxf(l2[3], l2[4]), l2[5]));

        // first index equal to max
        int c1[18];
#pragma unroll
        for (int j = 0; j < 17; ++j) {
            int x = (a[3 * j]     == m) ? (3 * j)     : 63;
            int y = (a[3 * j + 1] == m) ? (3 * j + 1) : 63;
            int z = (a[3 * j + 2] == m) ? (3 * j + 2) : 63;
            c1[j] = min(min(x, y), z);
        }
        c1[17] = (a[51] == m) ? 51 : 63;
        int c2[6];
#pragma unroll
        for (int j = 0; j < 6; ++j)
            c2[j] = min(min(c1[3 * j], c1[3 * j + 1]), c1[3 * j + 2]);
        const int idx = min(min(min(c2[0], c2[1]), c2[2]),
                            min(min(c2[3], c2[4]), c2[5]));

        if (lane < CTAGS)
            bp[(size_t)p * CTAGS + lane] = (unsigned char)idx;
    }
}

// ---------------------------------------------------------------------------
// K4: backtrack. Stage this batch's bp + masks in LDS, chase, write path.
// ---------------------------------------------------------------------------
__global__ __launch_bounds__(64) void viterbi_bt(
    const unsigned char* __restrict__ bp, const int* __restrict__ masks,
    const int* __restrict__ btag, float* __restrict__ out)
{
    const int b   = blockIdx.x;
    const int tid = threadIdx.x;

    __shared__ __align__(16) unsigned char bpl[SEQL * CTAGS]; // 26624 B
    __shared__ int ml[SEQL];
    __shared__ unsigned char pathb[SEQL];

    const uint4* src = (const uint4*)(bp + (size_t)b * SEQL * CTAGS);
    for (int i = tid; i < SEQL * CTAGS / 16; i += 64)
        ((uint4*)bpl)[i] = src[i];
    for (int i = tid; i < SEQL; i += 64) ml[i] = masks[(size_t)b * SEQL + i];
    __syncthreads();

    int c = btag[b];
    if (tid == 0) pathb[SEQL - 1] = (unsigned char)c;
    for (int i = SEQL - 2; i >= 0; --i) {
        int nxt = bpl[(i + 1) * CTAGS + c];
        c = ml[i] ? nxt : c;
        if (tid == 0) pathb[i] = (unsigned char)c;
    }
    __syncthreads();

    float* po = out + BATCH + (size_t)b * SEQL;
#pragma unroll
    for (int i = 0; i < 8; ++i)
        po[i * 64 + tid] = (float)pathb[i * 64 + tid];
}

// ---------------------------------------------------------------------------
extern "C" void kernel_launch(void* const* d_in, const int* in_sizes, int n_in,
                              void* d_out, int out_size, void* d_ws, size_t ws_size,
                              hipStream_t stream)
{
    const float* features = (const float*)d_in[0];
    const int*   masks    = (const int*)d_in[1];
    const float* W        = (const float*)d_in[2];
    const float* bias     = (const float*)d_in[3];
    const float* T        = (const float*)d_in[4];

    float* out = (float*)d_out;

    // workspace: emit (13.6 MB, later aliased as s_hist) | bp (3.4 MB) | btag
    const size_t emit_bytes = (size_t)BATCH * SEQL * CTAGS * sizeof(float);
    const size_t bp_bytes   = (size_t)BATCH * SEQL * CTAGS;
    float*         emit   = (float*)d_ws;
    float*         s_hist = emit;  // alias: scan consumes emit[t] before overwrite
    unsigned char* bpws   = (unsigned char*)d_ws + emit_bytes;
    int*           btag   = (int*)((unsigned char*)d_ws + emit_bytes + bp_bytes);

    emit_gemm2<<<BATCH * SEQL / (4 * RPW), 256, 0, stream>>>(features, W, bias, emit);
    viterbi_scan<<<BATCH, 64, 0, stream>>>(emit, masks, T, s_hist, out, btag);
    bp_compute<<<BATCH * SEQL / (4 * PPW), 256, 0, stream>>>(s_hist, T, bpws);
    viterbi_bt<<<BATCH, 64, 0, stream>>>(bpws, masks, btag, out);
}